// Round 2
// baseline (423.928 us; speedup 1.0000x reference)
//
#include <hip/hip_runtime.h>
#include <stdint.h>

#define DM 4096
#define NH 32
#define DK 128

typedef __attribute__((ext_vector_type(4))) float f32x4;
typedef __attribute__((ext_vector_type(8))) short s16x8;
typedef __attribute__((ext_vector_type(8))) unsigned short u16x8;
typedef __attribute__((ext_vector_type(4))) unsigned short u16x4;

__device__ __forceinline__ unsigned short f2bf(float f) {
  union { float f; unsigned u; } c; c.f = f;
  unsigned u = c.u;
  u += 0x7FFFu + ((u >> 16) & 1u);   // round-to-nearest-even
  return (unsigned short)(u >> 16);
}
__device__ __forceinline__ float bf2f(unsigned short h) {
  union { unsigned u; float f; } c; c.u = ((unsigned)h) << 16;
  return c.f;
}

// ---------- kernel 0: x (128x4096 f32) -> blocked bf16 hi/lo planes ----------
// layout: xbt[kg][s][e], kg in [0,512), s in [0,128), e in [0,8): value x[s][kg*8+e]
__global__ __launch_bounds__(256) void k0_xsplit(const float* __restrict__ x,
                                                 unsigned short* __restrict__ xh,
                                                 unsigned short* __restrict__ xl) {
  int g = blockIdx.x * 256 + threadIdx.x;  // 65536 threads
  int kg = g & 511, s = g >> 9;
  const float* px = x + (size_t)s * DM + kg * 8;
  f32x4 v0 = *(const f32x4*)px;
  f32x4 v1 = *(const f32x4*)(px + 4);
  u16x8 hi, lo;
#pragma unroll
  for (int j = 0; j < 8; ++j) {
    float v = (j < 4) ? v0[j] : v1[j - 4];
    unsigned short hh = f2bf(v);
    hi[j] = hh;
    lo[j] = f2bf(v - bf2f(hh));
  }
  size_t o = ((size_t)kg * 128 + s) * 8;
  *(u16x8*)(xh + o) = hi;
  *(u16x8*)(xl + o) = lo;
}

// ---------- kernel 1: proj partials = W_all . x^T (split-K=2) ----------
// grid 384 = 192 rowblocks x 2 k-chunks; block 256 = 4 waves, wave owns 16 rows.
// stores fp32 partials: pp[(kc*3+w)*524288 + off]
//   w in {Q,K}: off = (h*128 + s)*128 + d   (layout [h][s][d])
//   w == V   : off = (h*128 + d)*128 + s   (layout [h][d][s])
__global__ __launch_bounds__(256) void k1_proj(const float* __restrict__ Q,
                                               const float* __restrict__ K,
                                               const float* __restrict__ V,
                                               const unsigned short* __restrict__ xh,
                                               const unsigned short* __restrict__ xl,
                                               float* __restrict__ pp) {
  __shared__ __align__(16) unsigned short xs[8192];  // 16KB: [plane2][kg4][s128][8]
  int bid = blockIdx.x;
  int rb = bid >> 1, kc = bid & 1;
  int r0 = rb * 64;
  int w = r0 >> 12;        // 0:Q 1:K 2:V
  int rloc = r0 & 4095;
  const float* W = (w == 0) ? Q : ((w == 1) ? K : V);
  int tid = threadIdx.x;
  int wave = tid >> 6, lane = tid & 63;
  int l15 = lane & 15, lg = lane >> 4;
  int rwb = rloc + wave * 16;
  const float* arow = W + (size_t)(rwb + l15) * DM + lg * 8;
  f32x4 acc[8];
#pragma unroll
  for (int i = 0; i < 8; ++i) acc[i] = (f32x4)0.f;
  int kbase = kc * 2048;
  for (int stepi = 0; stepi < 64; ++stepi) {
    int kk = kbase + stepi * 32;
    __syncthreads();
    {
      const u16x8* sh = (const u16x8*)(xh + (size_t)kk * 128);
      const u16x8* sl = (const u16x8*)(xl + (size_t)kk * 128);
      u16x8* d0 = (u16x8*)xs;
#pragma unroll
      for (int i = 0; i < 2; ++i) {
        int ch = i * 256 + tid;
        d0[ch] = sh[ch];        // hi plane -> xs[0..4096)
        d0[512 + ch] = sl[ch];  // lo plane -> xs[4096..8192)
      }
    }
    __syncthreads();
    // A fragment: 8 consecutive fp32 of this wave's W row, split hi/lo
    const float* ap = arow + kk;
    f32x4 a0 = *(const f32x4*)ap;
    f32x4 a1 = *(const f32x4*)(ap + 4);
    s16x8 Ahi, Alo;
#pragma unroll
    for (int j = 0; j < 8; ++j) {
      float v = (j < 4) ? a0[j] : a1[j - 4];
      unsigned short hh = f2bf(v);
      Ahi[j] = (short)hh;
      Alo[j] = (short)f2bf(v - bf2f(hh));
    }
#pragma unroll
    for (int nt = 0; nt < 8; ++nt) {
      int off = ((lg * 128) + nt * 16 + l15) * 8;
      s16x8 bh = *(const s16x8*)&xs[off];
      s16x8 bl = *(const s16x8*)&xs[4096 + off];
      acc[nt] = __builtin_amdgcn_mfma_f32_16x16x32_bf16(Ahi, bh, acc[nt], 0, 0, 0);
      acc[nt] = __builtin_amdgcn_mfma_f32_16x16x32_bf16(Ahi, bl, acc[nt], 0, 0, 0);
      acc[nt] = __builtin_amdgcn_mfma_f32_16x16x32_bf16(Alo, bh, acc[nt], 0, 0, 0);
    }
  }
  int h = rwb >> 7;
  int dbase = (rwb & 127) + (lg << 2);
  size_t base = (size_t)(kc * 3 + w) * 524288;
  if (w < 2) {
#pragma unroll
    for (int nt = 0; nt < 8; ++nt) {
      int s = nt * 16 + l15;
      *(f32x4*)(pp + base + (size_t)(h * 128 + s) * 128 + dbase) = acc[nt];
    }
  } else {
#pragma unroll
    for (int nt = 0; nt < 8; ++nt) {
      int s = nt * 16 + l15;
#pragma unroll
      for (int r = 0; r < 4; ++r)
        pp[base + (size_t)(h * 128 + dbase + r) * 128 + s] = acc[nt][r];
    }
  }
}

// ---------- kernel 2: per-head attention ----------
// grid 32 (one head), block 256 = 4 waves, wave owns 32 q-rows.
// LDS 64KB: Kb blocked [dg16][k128][8] at [0,16384); Vb blocked [kg16][d128][8]
// at [16384,32768); P (blocked [kg16][q128][8]) aliases Kb after scores.
__global__ __launch_bounds__(256) void k2_attn(const float* __restrict__ pp,
                                               unsigned short* __restrict__ att) {
  __shared__ __align__(16) unsigned short lds[32768];
  int h = blockIdx.x;
  int tid = threadIdx.x, wave = tid >> 6, lane = tid & 63;
  int l15 = lane & 15, lg = lane >> 4;
  const float* pk0 = pp + (size_t)1 * 524288 + (size_t)h * 16384;
  const float* pk1 = pp + (size_t)4 * 524288 + (size_t)h * 16384;
  const float* pv0 = pp + (size_t)2 * 524288 + (size_t)h * 16384;
  const float* pv1 = pp + (size_t)5 * 524288 + (size_t)h * 16384;
  for (int g = tid; g < 2048; g += 256) {
    int dg = g & 15, k = g >> 4;
    size_t so = (size_t)k * 128 + dg * 8;
    f32x4 u0 = *(const f32x4*)(pk0 + so);
    f32x4 u1 = *(const f32x4*)(pk0 + so + 4);
    f32x4 w0 = *(const f32x4*)(pk1 + so);
    f32x4 w1 = *(const f32x4*)(pk1 + so + 4);
    u16x8 kb;
#pragma unroll
    for (int j = 0; j < 4; ++j) {
      kb[j] = f2bf(u0[j] + w0[j]);
      kb[4 + j] = f2bf(u1[j] + w1[j]);
    }
    *(u16x8*)&lds[(size_t)(dg * 128 + k) * 8] = kb;
    int kg = g & 15, d = g >> 4;
    size_t vo = (size_t)d * 128 + kg * 8;
    f32x4 x0 = *(const f32x4*)(pv0 + vo);
    f32x4 x1 = *(const f32x4*)(pv0 + vo + 4);
    f32x4 y0 = *(const f32x4*)(pv1 + vo);
    f32x4 y1 = *(const f32x4*)(pv1 + vo + 4);
    u16x8 vb;
#pragma unroll
    for (int j = 0; j < 4; ++j) {
      vb[j] = f2bf(x0[j] + y0[j]);
      vb[4 + j] = f2bf(x1[j] + y1[j]);
    }
    *(u16x8*)&lds[16384 + (size_t)(kg * 128 + d) * 8] = vb;
  }
  __syncthreads();

  int qbase = wave * 32;
  const float* pq0 = pp + (size_t)h * 16384;
  const float* pq1 = pp + (size_t)3 * 524288 + (size_t)h * 16384;
  const float RS = 0.08838834764831845f;  // 1/sqrt(128)
  f32x4 sc[2][8];
#pragma unroll
  for (int a = 0; a < 2; ++a)
#pragma unroll
    for (int b = 0; b < 8; ++b) sc[a][b] = (f32x4)0.f;

  for (int ks = 0; ks < 4; ++ks) {
    s16x8 qhi[2], qlo[2];
#pragma unroll
    for (int qt = 0; qt < 2; ++qt) {
      int q = qbase + qt * 16 + l15;
      size_t qo = (size_t)q * 128 + ks * 32 + lg * 8;
      f32x4 u0 = *(const f32x4*)(pq0 + qo);
      f32x4 u1 = *(const f32x4*)(pq0 + qo + 4);
      f32x4 w0 = *(const f32x4*)(pq1 + qo);
      f32x4 w1 = *(const f32x4*)(pq1 + qo + 4);
#pragma unroll
      for (int j = 0; j < 8; ++j) {
        float v = ((j < 4) ? (u0[j] + w0[j]) : (u1[j - 4] + w1[j - 4])) * RS;
        unsigned short hh = f2bf(v);
        qhi[qt][j] = (short)hh;
        qlo[qt][j] = (short)f2bf(v - bf2f(hh));
      }
    }
#pragma unroll
    for (int nt = 0; nt < 8; ++nt) {
      s16x8 kb = *(const s16x8*)&lds[(size_t)((ks * 4 + lg) * 128 + nt * 16 + l15) * 8];
#pragma unroll
      for (int qt = 0; qt < 2; ++qt) {
        sc[qt][nt] = __builtin_amdgcn_mfma_f32_16x16x32_bf16(qhi[qt], kb, sc[qt][nt], 0, 0, 0);
        sc[qt][nt] = __builtin_amdgcn_mfma_f32_16x16x32_bf16(qlo[qt], kb, sc[qt][nt], 0, 0, 0);
      }
    }
  }
  // masked softmax (keep k >= q), row distributed over 16 lanes x 8 ntiles
  float inv[2][4];
#pragma unroll
  for (int qt = 0; qt < 2; ++qt) {
#pragma unroll
    for (int r = 0; r < 4; ++r) {
      int q = qbase + qt * 16 + (lg << 2) + r;
      float m = -3.0e38f;
#pragma unroll
      for (int nt = 0; nt < 8; ++nt) {
        int k = nt * 16 + l15;
        float v = sc[qt][nt][r];
        if (k >= q) m = fmaxf(m, v);
      }
#pragma unroll
      for (int d = 1; d < 16; d <<= 1) m = fmaxf(m, __shfl_xor(m, d));
      float ssum = 0.f;
#pragma unroll
      for (int nt = 0; nt < 8; ++nt) {
        int k = nt * 16 + l15;
        float v = sc[qt][nt][r];
        float e = (k >= q) ? __expf(v - m) : 0.f;
        sc[qt][nt][r] = e;
        ssum += e;
      }
#pragma unroll
      for (int d = 1; d < 16; d <<= 1) ssum += __shfl_xor(ssum, d);
      inv[qt][r] = 1.f / ssum;
    }
  }
  __syncthreads();  // all waves done reading Kb
  // write P (alias Kb): blocked [k/8][q][k%8]
#pragma unroll
  for (int qt = 0; qt < 2; ++qt)
#pragma unroll
    for (int nt = 0; nt < 8; ++nt) {
      int k = nt * 16 + l15;
#pragma unroll
      for (int r = 0; r < 4; ++r) {
        int q = qbase + qt * 16 + (lg << 2) + r;
        lds[(size_t)((k >> 3) * 128 + q) * 8 + (k & 7)] = f2bf(sc[qt][nt][r] * inv[qt][r]);
      }
    }
  __syncthreads();
  // PV
  f32x4 o[2][8];
#pragma unroll
  for (int a = 0; a < 2; ++a)
#pragma unroll
    for (int b = 0; b < 8; ++b) o[a][b] = (f32x4)0.f;
  for (int ks = 0; ks < 4; ++ks) {
    s16x8 pa[2];
#pragma unroll
    for (int qt = 0; qt < 2; ++qt)
      pa[qt] = *(const s16x8*)&lds[(size_t)((ks * 4 + lg) * 128 + qbase + qt * 16 + l15) * 8];
#pragma unroll
    for (int nt = 0; nt < 8; ++nt) {
      s16x8 vb = *(const s16x8*)&lds[16384 + (size_t)((ks * 4 + lg) * 128 + nt * 16 + l15) * 8];
      o[0][nt] = __builtin_amdgcn_mfma_f32_16x16x32_bf16(pa[0], vb, o[0][nt], 0, 0, 0);
      o[1][nt] = __builtin_amdgcn_mfma_f32_16x16x32_bf16(pa[1], vb, o[1][nt], 0, 0, 0);
    }
  }
  // store att_T[d][j], j = h*128 + q, bf16
#pragma unroll
  for (int qt = 0; qt < 2; ++qt)
#pragma unroll
    for (int nt = 0; nt < 8; ++nt) {
      int d = nt * 16 + l15;
      int q = qbase + qt * 16 + (lg << 2);
      size_t j = (size_t)h * 128 + q;
      u16x4 pk;
#pragma unroll
      for (int r = 0; r < 4; ++r) pk[r] = f2bf(o[qt][nt][r]);
      *(u16x4*)(att + (size_t)d * DM + j) = pk;
    }
}

// ---------- kernel 3: out = O @ att  (4096x128 fp32) ----------
// grid 256 rowblocks of 16; block 256 = 4 waves, wave owns 32 cols.
__global__ __launch_bounds__(256) void k3_out(const float* __restrict__ O,
                                              const unsigned short* __restrict__ att,
                                              float* __restrict__ out) {
  int rb = blockIdx.x;
  int r0 = rb * 16;
  int tid = threadIdx.x, wave = tid >> 6, lane = tid & 63;
  int l15 = lane & 15, lg = lane >> 4;
  const float* arow = O + (size_t)(r0 + l15) * DM + lg * 8;
  int c0 = wave * 32;
  f32x4 acc0 = (f32x4)0.f, acc1 = (f32x4)0.f;
  const unsigned short* b0 = att + (size_t)(c0 + l15) * DM + lg * 8;
  const unsigned short* b1 = att + (size_t)(c0 + 16 + l15) * DM + lg * 8;
  for (int ks = 0; ks < 128; ++ks) {
    int j0 = ks * 32;
    f32x4 a0 = *(const f32x4*)(arow + j0);
    f32x4 a1 = *(const f32x4*)(arow + j0 + 4);
    s16x8 Ahi, Alo;
#pragma unroll
    for (int j = 0; j < 8; ++j) {
      float v = (j < 4) ? a0[j] : a1[j - 4];
      unsigned short hh = f2bf(v);
      Ahi[j] = (short)hh;
      Alo[j] = (short)f2bf(v - bf2f(hh));
    }
    s16x8 v0 = *(const s16x8*)(b0 + j0);
    s16x8 v1 = *(const s16x8*)(b1 + j0);
    acc0 = __builtin_amdgcn_mfma_f32_16x16x32_bf16(Ahi, v0, acc0, 0, 0, 0);
    acc0 = __builtin_amdgcn_mfma_f32_16x16x32_bf16(Alo, v0, acc0, 0, 0, 0);
    acc1 = __builtin_amdgcn_mfma_f32_16x16x32_bf16(Ahi, v1, acc1, 0, 0, 0);
    acc1 = __builtin_amdgcn_mfma_f32_16x16x32_bf16(Alo, v1, acc1, 0, 0, 0);
  }
#pragma unroll
  for (int r = 0; r < 4; ++r) {
    int row = r0 + (lg << 2) + r;
    out[(size_t)row * 128 + c0 + l15] = acc0[r];
    out[(size_t)row * 128 + c0 + 16 + l15] = acc1[r];
  }
}

extern "C" void kernel_launch(void* const* d_in, const int* in_sizes, int n_in,
                              void* d_out, int out_size, void* d_ws, size_t ws_size,
                              hipStream_t stream) {
  const float* Q = (const float*)d_in[0];
  const float* K = (const float*)d_in[1];
  const float* V = (const float*)d_in[2];
  const float* O = (const float*)d_in[3];
  const float* x = (const float*)d_in[4];
  float* out = (float*)d_out;
  uint8_t* ws = (uint8_t*)d_ws;
  unsigned short* xh = (unsigned short*)ws;                        // 1 MB
  unsigned short* xl = (unsigned short*)(ws + (1u << 20));         // 1 MB
  unsigned short* att = (unsigned short*)(ws + (2u << 20));        // 1 MB
  float* pp = (float*)(ws + (3u << 20));                           // 12.6 MB
  hipLaunchKernelGGL(k0_xsplit, dim3(256), dim3(256), 0, stream, x, xh, xl);
  hipLaunchKernelGGL(k1_proj, dim3(384), dim3(256), 0, stream, Q, K, V, xh, xl, pp);
  hipLaunchKernelGGL(k2_attn, dim3(32), dim3(256), 0, stream, pp, att);
  hipLaunchKernelGGL(k3_out, dim3(256), dim3(256), 0, stream, O, att, out);
}

// Round 3
// 318.785 us; speedup vs baseline: 1.3298x; 1.3298x over previous
//
#include <hip/hip_runtime.h>
#include <stdint.h>

#define DM 4096

typedef __attribute__((ext_vector_type(4))) float f32x4;
typedef __attribute__((ext_vector_type(8))) short s16x8;
typedef __attribute__((ext_vector_type(8))) unsigned short u16x8;
typedef __attribute__((ext_vector_type(4))) unsigned short u16x4;

__device__ __forceinline__ unsigned short f2bf(float f) {
  union { float f; unsigned u; } c; c.f = f;
  unsigned u = c.u;
  u += 0x7FFFu + ((u >> 16) & 1u);   // round-to-nearest-even
  return (unsigned short)(u >> 16);
}
__device__ __forceinline__ float bf2f(unsigned short h) {
  union { unsigned u; float f; } c; c.u = ((unsigned)h) << 16;
  return c.f;
}

// split fp32 -> bf16 hi (truncated) + bf16 lo (RNE of residual)
__device__ __forceinline__ void splitbf(float v, short& hi, short& lo) {
  union { float f; unsigned u; } c; c.f = v;
  unsigned uh = c.u & 0xFFFF0000u;
  hi = (short)(uh >> 16);
  union { unsigned u; float f; } d; d.u = uh;
  lo = (short)f2bf(v - d.f);
}

// ---------- kernel 0: x (128x4096 f32) -> blocked bf16 hi plane ----------
// layout: xh[kg][s][e], kg in [0,512), s in [0,128), e in [0,8): x[s][kg*8+e]
__global__ __launch_bounds__(256) void k0_xsplit(const float* __restrict__ x,
                                                 unsigned short* __restrict__ xh) {
  int g = blockIdx.x * 256 + threadIdx.x;  // 65536 threads
  int kg = g & 511, s = g >> 9;
  const float* px = x + (size_t)s * DM + kg * 8;
  f32x4 v0 = *(const f32x4*)px;
  f32x4 v1 = *(const f32x4*)(px + 4);
  u16x8 hi;
#pragma unroll
  for (int j = 0; j < 8; ++j) {
    float v = (j < 4) ? v0[j] : v1[j - 4];
    hi[j] = f2bf(v);
  }
  *(u16x8*)(xh + ((size_t)kg * 128 + s) * 8) = hi;
}

// ---------- kernel 1: proj partials = W_all . x^T (split-K=2, pipelined) ----------
// grid 384 = 192 rowblocks x 2 k-chunks; block 256 = 4 waves, wave owns 16 rows.
// depth-2 register prefetch of A (HBM) and x (L2); x staged 8KB/iter in LDS.
// stores fp32 partials pp[(kc*3+w)*524288 + off]:
//   w in {Q,K}: off = (h*128 + s)*128 + d   | w == V: off = (h*128 + d)*128 + s
__global__ __launch_bounds__(256) void k1_proj(const float* __restrict__ Q,
                                               const float* __restrict__ K,
                                               const float* __restrict__ V,
                                               const unsigned short* __restrict__ xh,
                                               float* __restrict__ pp) {
  __shared__ __align__(16) unsigned short xs[4096];  // 8KB: [kg4][s128][8]
  int bid = blockIdx.x;
  int rb = bid >> 1, kc = bid & 1;
  int r0 = rb * 64;
  int w = r0 >> 12;        // 0:Q 1:K 2:V
  int rloc = r0 & 4095;
  const float* W = (w == 0) ? Q : ((w == 1) ? K : V);
  int tid = threadIdx.x;
  int wave = tid >> 6, lane = tid & 63;
  int l15 = lane & 15, lg = lane >> 4;
  int rwb = rloc + wave * 16;
  const float* arow = W + (size_t)(rwb + l15) * DM + lg * 8;
  int kbase = kc * 2048;
  f32x4 acc[8];
#pragma unroll
  for (int i = 0; i < 8; ++i) acc[i] = (f32x4)0.f;

  u16x8 xA[2], xB[2];
  f32x4 aA[2], aB[2];
  auto loadx = [&](u16x8* xb, int kk) {
    const u16x8* s = (const u16x8*)(xh + (size_t)kk * 128);
    xb[0] = s[tid];
    xb[1] = s[256 + tid];
  };
  auto loada = [&](f32x4* ab, int kk) {
    ab[0] = *(const f32x4*)(arow + kk);
    ab[1] = *(const f32x4*)(arow + kk + 4);
  };
  loadx(xA, kbase);      loada(aA, kbase);
  loadx(xB, kbase + 32); loada(aB, kbase + 32);

  auto step = [&](u16x8* xb, f32x4* ab, int kkp) {
    __syncthreads();                       // xs free (prev readers done)
    ((u16x8*)xs)[tid] = xb[0];             // ds_write staged x (waits its vmcnt)
    ((u16x8*)xs)[256 + tid] = xb[1];
    s16x8 Ahi, Alo;
#pragma unroll
    for (int j = 0; j < 8; ++j) {
      float v = (j < 4) ? ab[0][j] : ab[1][j - 4];
      short h, l; splitbf(v, h, l);
      Ahi[j] = h; Alo[j] = l;
    }
    loadx(xb, kkp);                        // issue prefetch (t+2) — stays in flight
    loada(ab, kkp);
    __syncthreads();                       // xs ready
#pragma unroll
    for (int nt = 0; nt < 8; ++nt) {
      s16x8 bh = *(const s16x8*)&xs[((lg * 128) + nt * 16 + l15) * 8];
      acc[nt] = __builtin_amdgcn_mfma_f32_16x16x32_bf16(Ahi, bh, acc[nt], 0, 0, 0);
      acc[nt] = __builtin_amdgcn_mfma_f32_16x16x32_bf16(Alo, bh, acc[nt], 0, 0, 0);
    }
  };

  for (int t = 0; t < 64; t += 2) {
    int kk0 = kbase + t * 32;
    step(xA, aA, (t + 2 < 64) ? kk0 + 64 : kk0);
    step(xB, aB, (t + 3 < 64) ? kk0 + 96 : kk0 + 32);
  }

  int h = rwb >> 7;
  int dbase = (rwb & 127) + (lg << 2);
  size_t base = (size_t)(kc * 3 + w) * 524288;
  if (w < 2) {
#pragma unroll
    for (int nt = 0; nt < 8; ++nt) {
      int s = nt * 16 + l15;
      *(f32x4*)(pp + base + (size_t)(h * 128 + s) * 128 + dbase) = acc[nt];
    }
  } else {
#pragma unroll
    for (int nt = 0; nt < 8; ++nt) {
      int s = nt * 16 + l15;
#pragma unroll
      for (int r = 0; r < 4; ++r)
        pp[base + (size_t)(h * 128 + dbase + r) * 128 + s] = acc[nt][r];
    }
  }
}

// ---------- kernel 2: per-head attention ----------
// grid 32 (one head), block 256 = 4 waves, wave owns 32 q-rows.
// LDS 64KB: Kb blocked [dg16][k128][8] at [0,16384); Vb blocked [kg16][d128][8]
// at [16384,32768); P (blocked [kg16][q128][8]) aliases Kb after scores.
__global__ __launch_bounds__(256) void k2_attn(const float* __restrict__ pp,
                                               unsigned short* __restrict__ att) {
  __shared__ __align__(16) unsigned short lds[32768];
  int h = blockIdx.x;
  int tid = threadIdx.x, wave = tid >> 6, lane = tid & 63;
  int l15 = lane & 15, lg = lane >> 4;
  const float* pk0 = pp + (size_t)1 * 524288 + (size_t)h * 16384;
  const float* pk1 = pp + (size_t)4 * 524288 + (size_t)h * 16384;
  const float* pv0 = pp + (size_t)2 * 524288 + (size_t)h * 16384;
  const float* pv1 = pp + (size_t)5 * 524288 + (size_t)h * 16384;
  for (int g = tid; g < 2048; g += 256) {
    int dg = g & 15, k = g >> 4;
    size_t so = (size_t)k * 128 + dg * 8;
    f32x4 u0 = *(const f32x4*)(pk0 + so);
    f32x4 u1 = *(const f32x4*)(pk0 + so + 4);
    f32x4 w0 = *(const f32x4*)(pk1 + so);
    f32x4 w1 = *(const f32x4*)(pk1 + so + 4);
    u16x8 kb;
#pragma unroll
    for (int j = 0; j < 4; ++j) {
      kb[j] = f2bf(u0[j] + w0[j]);
      kb[4 + j] = f2bf(u1[j] + w1[j]);
    }
    *(u16x8*)&lds[(size_t)(dg * 128 + k) * 8] = kb;
    int kg = g & 15, d = g >> 4;
    size_t vo = (size_t)d * 128 + kg * 8;
    f32x4 x0 = *(const f32x4*)(pv0 + vo);
    f32x4 x1 = *(const f32x4*)(pv0 + vo + 4);
    f32x4 y0 = *(const f32x4*)(pv1 + vo);
    f32x4 y1 = *(const f32x4*)(pv1 + vo + 4);
    u16x8 vb;
#pragma unroll
    for (int j = 0; j < 4; ++j) {
      vb[j] = f2bf(x0[j] + y0[j]);
      vb[4 + j] = f2bf(x1[j] + y1[j]);
    }
    *(u16x8*)&lds[16384 + (size_t)(kg * 128 + d) * 8] = vb;
  }
  __syncthreads();

  int qbase = wave * 32;
  const float* pq0 = pp + (size_t)h * 16384;
  const float* pq1 = pp + (size_t)3 * 524288 + (size_t)h * 16384;
  const float RS = 0.08838834764831845f;  // 1/sqrt(128)
  f32x4 sc[2][8];
#pragma unroll
  for (int a = 0; a < 2; ++a)
#pragma unroll
    for (int b = 0; b < 8; ++b) sc[a][b] = (f32x4)0.f;

  for (int ks = 0; ks < 4; ++ks) {
    s16x8 qhi[2], qlo[2];
#pragma unroll
    for (int qt = 0; qt < 2; ++qt) {
      int q = qbase + qt * 16 + l15;
      size_t qo = (size_t)q * 128 + ks * 32 + lg * 8;
      f32x4 u0 = *(const f32x4*)(pq0 + qo);
      f32x4 u1 = *(const f32x4*)(pq0 + qo + 4);
      f32x4 w0 = *(const f32x4*)(pq1 + qo);
      f32x4 w1 = *(const f32x4*)(pq1 + qo + 4);
#pragma unroll
      for (int j = 0; j < 8; ++j) {
        float v = ((j < 4) ? (u0[j] + w0[j]) : (u1[j - 4] + w1[j - 4])) * RS;
        unsigned short hh = f2bf(v);
        qhi[qt][j] = (short)hh;
        qlo[qt][j] = (short)f2bf(v - bf2f(hh));
      }
    }
#pragma unroll
    for (int nt = 0; nt < 8; ++nt) {
      s16x8 kb = *(const s16x8*)&lds[(size_t)((ks * 4 + lg) * 128 + nt * 16 + l15) * 8];
#pragma unroll
      for (int qt = 0; qt < 2; ++qt) {
        sc[qt][nt] = __builtin_amdgcn_mfma_f32_16x16x32_bf16(qhi[qt], kb, sc[qt][nt], 0, 0, 0);
        sc[qt][nt] = __builtin_amdgcn_mfma_f32_16x16x32_bf16(qlo[qt], kb, sc[qt][nt], 0, 0, 0);
      }
    }
  }
  // masked softmax (keep k >= q), row distributed over 16 lanes x 8 ntiles
  float inv[2][4];
#pragma unroll
  for (int qt = 0; qt < 2; ++qt) {
#pragma unroll
    for (int r = 0; r < 4; ++r) {
      int q = qbase + qt * 16 + (lg << 2) + r;
      float m = -3.0e38f;
#pragma unroll
      for (int nt = 0; nt < 8; ++nt) {
        int k = nt * 16 + l15;
        float v = sc[qt][nt][r];
        if (k >= q) m = fmaxf(m, v);
      }
#pragma unroll
      for (int d = 1; d < 16; d <<= 1) m = fmaxf(m, __shfl_xor(m, d));
      float ssum = 0.f;
#pragma unroll
      for (int nt = 0; nt < 8; ++nt) {
        int k = nt * 16 + l15;
        float v = sc[qt][nt][r];
        float e = (k >= q) ? __expf(v - m) : 0.f;
        sc[qt][nt][r] = e;
        ssum += e;
      }
#pragma unroll
      for (int d = 1; d < 16; d <<= 1) ssum += __shfl_xor(ssum, d);
      inv[qt][r] = 1.f / ssum;
    }
  }
  __syncthreads();  // all waves done reading Kb
  // write P (alias Kb): blocked [k/8][q][k%8]
#pragma unroll
  for (int qt = 0; qt < 2; ++qt)
#pragma unroll
    for (int nt = 0; nt < 8; ++nt) {
      int k = nt * 16 + l15;
#pragma unroll
      for (int r = 0; r < 4; ++r) {
        int q = qbase + qt * 16 + (lg << 2) + r;
        lds[(size_t)((k >> 3) * 128 + q) * 8 + (k & 7)] = f2bf(sc[qt][nt][r] * inv[qt][r]);
      }
    }
  __syncthreads();
  // PV
  f32x4 o[2][8];
#pragma unroll
  for (int a = 0; a < 2; ++a)
#pragma unroll
    for (int b = 0; b < 8; ++b) o[a][b] = (f32x4)0.f;
  for (int ks = 0; ks < 4; ++ks) {
    s16x8 pa[2];
#pragma unroll
    for (int qt = 0; qt < 2; ++qt)
      pa[qt] = *(const s16x8*)&lds[(size_t)((ks * 4 + lg) * 128 + qbase + qt * 16 + l15) * 8];
#pragma unroll
    for (int nt = 0; nt < 8; ++nt) {
      s16x8 vb = *(const s16x8*)&lds[16384 + (size_t)((ks * 4 + lg) * 128 + nt * 16 + l15) * 8];
      o[0][nt] = __builtin_amdgcn_mfma_f32_16x16x32_bf16(pa[0], vb, o[0][nt], 0, 0, 0);
      o[1][nt] = __builtin_amdgcn_mfma_f32_16x16x32_bf16(pa[1], vb, o[1][nt], 0, 0, 0);
    }
  }
  // store att_T[d][j], j = h*128 + q, bf16
#pragma unroll
  for (int qt = 0; qt < 2; ++qt)
#pragma unroll
    for (int nt = 0; nt < 8; ++nt) {
      int d = nt * 16 + l15;
      int q = qbase + qt * 16 + (lg << 2);
      size_t j = (size_t)h * 128 + q;
      u16x4 pk;
#pragma unroll
      for (int r = 0; r < 4; ++r) pk[r] = f2bf(o[qt][nt][r]);
      *(u16x4*)(att + (size_t)d * DM + j) = pk;
    }
}

// ---------- kernel 3: out += O @ att (split-K=4, pipelined, atomic accumulate) ----
// grid 1024 = 256 rowblocks x 4 kc; block 256 = 4 waves, wave owns 32 cols.
__global__ __launch_bounds__(256) void k3_out(const float* __restrict__ O,
                                              const unsigned short* __restrict__ att,
                                              float* __restrict__ out) {
  int bid = blockIdx.x;
  int rb = bid >> 2, kc = bid & 3;
  int r0 = rb * 16;
  int kbase = kc * 1024;
  int tid = threadIdx.x, wave = tid >> 6, lane = tid & 63;
  int l15 = lane & 15, lg = lane >> 4;
  const float* arow = O + (size_t)(r0 + l15) * DM + lg * 8;
  int c0 = wave * 32;
  const unsigned short* b0p = att + (size_t)(c0 + l15) * DM + lg * 8;
  const unsigned short* b1p = att + (size_t)(c0 + 16 + l15) * DM + lg * 8;
  f32x4 acc0 = (f32x4)0.f, acc1 = (f32x4)0.f;

  f32x4 aA[2], aB[2];
  s16x8 bA0, bA1, bB0, bB1;
  auto load = [&](f32x4* ab, s16x8& b0, s16x8& b1, int j0) {
    ab[0] = *(const f32x4*)(arow + j0);
    ab[1] = *(const f32x4*)(arow + j0 + 4);
    b0 = *(const s16x8*)(b0p + j0);
    b1 = *(const s16x8*)(b1p + j0);
  };
  load(aA, bA0, bA1, kbase);
  load(aB, bB0, bB1, kbase + 32);

  auto step = [&](f32x4* ab, s16x8& b0, s16x8& b1, int j0p) {
    s16x8 Ahi, Alo;
#pragma unroll
    for (int j = 0; j < 8; ++j) {
      float v = (j < 4) ? ab[0][j] : ab[1][j - 4];
      short h, l; splitbf(v, h, l);
      Ahi[j] = h; Alo[j] = l;
    }
    s16x8 v0 = b0, v1 = b1;
    load(ab, b0, b1, j0p);     // prefetch t+2
    acc0 = __builtin_amdgcn_mfma_f32_16x16x32_bf16(Ahi, v0, acc0, 0, 0, 0);
    acc0 = __builtin_amdgcn_mfma_f32_16x16x32_bf16(Alo, v0, acc0, 0, 0, 0);
    acc1 = __builtin_amdgcn_mfma_f32_16x16x32_bf16(Ahi, v1, acc1, 0, 0, 0);
    acc1 = __builtin_amdgcn_mfma_f32_16x16x32_bf16(Alo, v1, acc1, 0, 0, 0);
  };

  for (int t = 0; t < 32; t += 2) {
    int j0 = kbase + t * 32;
    step(aA, bA0, bA1, (t + 2 < 32) ? j0 + 64 : j0);
    step(aB, bB0, bB1, (t + 3 < 32) ? j0 + 96 : j0 + 32);
  }
#pragma unroll
  for (int r = 0; r < 4; ++r) {
    int row = r0 + (lg << 2) + r;
    atomicAdd(&out[(size_t)row * 128 + c0 + l15], acc0[r]);
    atomicAdd(&out[(size_t)row * 128 + c0 + 16 + l15], acc1[r]);
  }
}

extern "C" void kernel_launch(void* const* d_in, const int* in_sizes, int n_in,
                              void* d_out, int out_size, void* d_ws, size_t ws_size,
                              hipStream_t stream) {
  const float* Q = (const float*)d_in[0];
  const float* K = (const float*)d_in[1];
  const float* V = (const float*)d_in[2];
  const float* O = (const float*)d_in[3];
  const float* x = (const float*)d_in[4];
  float* out = (float*)d_out;
  uint8_t* ws = (uint8_t*)d_ws;
  unsigned short* xh = (unsigned short*)ws;                        // 1 MB
  unsigned short* att = (unsigned short*)(ws + (1u << 20));        // 1 MB
  float* pp = (float*)(ws + (2u << 20));                           // 12 MB
  hipMemsetAsync(d_out, 0, (size_t)out_size * sizeof(float), stream);
  hipLaunchKernelGGL(k0_xsplit, dim3(256), dim3(256), 0, stream, x, xh);
  hipLaunchKernelGGL(k1_proj, dim3(384), dim3(256), 0, stream, Q, K, V, xh, pp);
  hipLaunchKernelGGL(k2_attn, dim3(32), dim3(256), 0, stream, pp, att);
  hipLaunchKernelGGL(k3_out, dim3(1024), dim3(256), 0, stream, O, att, out);
}

// Round 4
// 288.454 us; speedup vs baseline: 1.4697x; 1.1051x over previous
//
#include <hip/hip_runtime.h>
#include <stdint.h>

#define DM 4096

typedef __attribute__((ext_vector_type(4))) float f32x4;
typedef __attribute__((ext_vector_type(8))) short s16x8;
typedef __attribute__((ext_vector_type(8))) unsigned short u16x8;
typedef __attribute__((ext_vector_type(4))) unsigned short u16x4;

__device__ __forceinline__ unsigned short f2bf(float f) {
  union { float f; unsigned u; } c; c.f = f;
  unsigned u = c.u;
  u += 0x7FFFu + ((u >> 16) & 1u);   // round-to-nearest-even
  return (unsigned short)(u >> 16);
}
__device__ __forceinline__ float bf2f(unsigned short h) {
  union { unsigned u; float f; } c; c.u = ((unsigned)h) << 16;
  return c.f;
}

// split fp32 -> bf16 hi (truncated) + bf16 lo (RNE of residual)
__device__ __forceinline__ void splitbf(float v, short& hi, short& lo) {
  union { float f; unsigned u; } c; c.f = v;
  unsigned uh = c.u & 0xFFFF0000u;
  hi = (short)(uh >> 16);
  union { unsigned u; float f; } d; d.u = uh;
  lo = (short)f2bf(v - d.f);
}

// raw barrier: NO vmcnt drain (keeps HBM prefetches in flight across it)
__device__ __forceinline__ void wave_barrier_lgkm() {
  asm volatile("s_waitcnt lgkmcnt(0)" ::: "memory");
  __builtin_amdgcn_s_barrier();
}

// ---------- kernel 0: x (128x4096 f32) -> blocked bf16 hi plane ----------
// layout: xh[kg][s][e], kg in [0,512), s in [0,128), e in [0,8): x[s][kg*8+e]
__global__ __launch_bounds__(256) void k0_xsplit(const float* __restrict__ x,
                                                 unsigned short* __restrict__ xh) {
  int g = blockIdx.x * 256 + threadIdx.x;  // 65536 threads
  int kg = g & 511, s = g >> 9;
  const float* px = x + (size_t)s * DM + kg * 8;
  f32x4 v0 = *(const f32x4*)px;
  f32x4 v1 = *(const f32x4*)(px + 4);
  u16x8 hi;
#pragma unroll
  for (int j = 0; j < 8; ++j) {
    float v = (j < 4) ? v0[j] : v1[j - 4];
    hi[j] = f2bf(v);
  }
  *(u16x8*)(xh + ((size_t)kg * 128 + s) * 8) = hi;
}

// ---------- kernel 1: proj partials = W_all . x^T (split-K=2, depth-4 pipe) ----
// grid 384 = 192 rowblocks x 2 k-chunks; block 256 = 4 waves, wave owns 16 rows.
// Raw barriers (no vmcnt drain) + depth-4 register ring for A (HBM) and x (L2).
// stores fp32 partials pp[(kc*3+w)*524288 + off]:
//   w in {Q,K}: off = (h*128 + s)*128 + d   | w == V: off = (h*128 + d)*128 + s
__global__ __launch_bounds__(256) void k1_proj(const float* __restrict__ Q,
                                               const float* __restrict__ K,
                                               const float* __restrict__ V,
                                               const unsigned short* __restrict__ xh,
                                               float* __restrict__ pp) {
  __shared__ __align__(16) unsigned short xs[4096];  // 8KB: [kg4][s128][8]
  int bid = blockIdx.x;
  int rb = bid >> 1, kc = bid & 1;
  int r0 = rb * 64;
  int w = r0 >> 12;        // 0:Q 1:K 2:V
  int rloc = r0 & 4095;
  const float* W = (w == 0) ? Q : ((w == 1) ? K : V);
  int tid = threadIdx.x;
  int wave = tid >> 6, lane = tid & 63;
  int l15 = lane & 15, lg = lane >> 4;
  int rwb = rloc + wave * 16;
  const float* arow = W + (size_t)(rwb + l15) * DM + lg * 8;
  int kbase = kc * 2048;
  f32x4 acc[8];
#pragma unroll
  for (int i = 0; i < 8; ++i) acc[i] = (f32x4)0.f;

  u16x8 xb[4][2];
  f32x4 ab[4][2];
#pragma unroll
  for (int p = 0; p < 4; ++p) {
    int kk = kbase + p * 32;
    const u16x8* s = (const u16x8*)(xh + (size_t)kk * 128);
    xb[p][0] = s[tid];
    xb[p][1] = s[256 + tid];
    ab[p][0] = *(const f32x4*)(arow + kk);
    ab[p][1] = *(const f32x4*)(arow + kk + 4);
  }

  for (int tt = 0; tt < 16; ++tt) {
#pragma unroll
    for (int p = 0; p < 4; ++p) {
      int t = tt * 4 + p;
      wave_barrier_lgkm();                 // prev iter's ds_reads complete (WAR)
      ((u16x8*)xs)[tid] = xb[p][0];        // auto counted-vmcnt wait (L2, covered)
      ((u16x8*)xs)[256 + tid] = xb[p][1];
      s16x8 Ahi, Alo;
#pragma unroll
      for (int j = 0; j < 8; ++j) {
        float v = (j < 4) ? ab[p][0][j] : ab[p][1][j - 4];
        short h, l; splitbf(v, h, l);
        Ahi[j] = h; Alo[j] = l;
      }
      int tp = t + 4;
      int kkp = kbase + ((tp < 64) ? tp : 0) * 32;   // tail: dummy reload, unused
      {
        const u16x8* s = (const u16x8*)(xh + (size_t)kkp * 128);
        xb[p][0] = s[tid];
        xb[p][1] = s[256 + tid];
        ab[p][0] = *(const f32x4*)(arow + kkp);
        ab[p][1] = *(const f32x4*)(arow + kkp + 4);
      }
      wave_barrier_lgkm();                 // my ds_writes visible to all
#pragma unroll
      for (int nt = 0; nt < 8; ++nt) {
        s16x8 bh = *(const s16x8*)&xs[((lg * 128) + nt * 16 + l15) * 8];
        acc[nt] = __builtin_amdgcn_mfma_f32_16x16x32_bf16(Ahi, bh, acc[nt], 0, 0, 0);
        acc[nt] = __builtin_amdgcn_mfma_f32_16x16x32_bf16(Alo, bh, acc[nt], 0, 0, 0);
      }
    }
  }

  int h = rwb >> 7;
  int dbase = (rwb & 127) + (lg << 2);
  size_t base = (size_t)(kc * 3 + w) * 524288;
  if (w < 2) {
#pragma unroll
    for (int nt = 0; nt < 8; ++nt) {
      int s = nt * 16 + l15;
      *(f32x4*)(pp + base + (size_t)(h * 128 + s) * 128 + dbase) = acc[nt];
    }
  } else {
#pragma unroll
    for (int nt = 0; nt < 8; ++nt) {
      int s = nt * 16 + l15;
#pragma unroll
      for (int r = 0; r < 4; ++r)
        pp[base + (size_t)(h * 128 + dbase + r) * 128 + s] = acc[nt][r];
    }
  }
}

// ---------- kernel 2: per-head attention ----------
// grid 32 (one head), block 256 = 4 waves, wave owns 32 q-rows.
// LDS 64KB: Kb blocked [dg16][k128][8] at [0,16384); Vb blocked [kg16][d128][8]
// at [16384,32768); P (blocked [kg16][q128][8]) aliases Kb after scores.
// att output now BLOCKED: attb[j/8][c128][8], j = h*128+q (k-dim of k3), c = d.
__global__ __launch_bounds__(256) void k2_attn(const float* __restrict__ pp,
                                               unsigned short* __restrict__ att) {
  __shared__ __align__(16) unsigned short lds[32768];
  int h = blockIdx.x;
  int tid = threadIdx.x, wave = tid >> 6, lane = tid & 63;
  int l15 = lane & 15, lg = lane >> 4;
  const float* pk0 = pp + (size_t)1 * 524288 + (size_t)h * 16384;
  const float* pk1 = pp + (size_t)4 * 524288 + (size_t)h * 16384;
  const float* pv0 = pp + (size_t)2 * 524288 + (size_t)h * 16384;
  const float* pv1 = pp + (size_t)5 * 524288 + (size_t)h * 16384;
  for (int g = tid; g < 2048; g += 256) {
    int dg = g & 15, k = g >> 4;
    size_t so = (size_t)k * 128 + dg * 8;
    f32x4 u0 = *(const f32x4*)(pk0 + so);
    f32x4 u1 = *(const f32x4*)(pk0 + so + 4);
    f32x4 w0 = *(const f32x4*)(pk1 + so);
    f32x4 w1 = *(const f32x4*)(pk1 + so + 4);
    u16x8 kb;
#pragma unroll
    for (int j = 0; j < 4; ++j) {
      kb[j] = f2bf(u0[j] + w0[j]);
      kb[4 + j] = f2bf(u1[j] + w1[j]);
    }
    *(u16x8*)&lds[(size_t)(dg * 128 + k) * 8] = kb;
    int kg = g & 15, d = g >> 4;
    size_t vo = (size_t)d * 128 + kg * 8;
    f32x4 x0 = *(const f32x4*)(pv0 + vo);
    f32x4 x1 = *(const f32x4*)(pv0 + vo + 4);
    f32x4 y0 = *(const f32x4*)(pv1 + vo);
    f32x4 y1 = *(const f32x4*)(pv1 + vo + 4);
    u16x8 vb;
#pragma unroll
    for (int j = 0; j < 4; ++j) {
      vb[j] = f2bf(x0[j] + y0[j]);
      vb[4 + j] = f2bf(x1[j] + y1[j]);
    }
    *(u16x8*)&lds[16384 + (size_t)(kg * 128 + d) * 8] = vb;
  }
  __syncthreads();

  int qbase = wave * 32;
  const float* pq0 = pp + (size_t)h * 16384;
  const float* pq1 = pp + (size_t)3 * 524288 + (size_t)h * 16384;
  const float RS = 0.08838834764831845f;  // 1/sqrt(128)
  f32x4 sc[2][8];
#pragma unroll
  for (int a = 0; a < 2; ++a)
#pragma unroll
    for (int b = 0; b < 8; ++b) sc[a][b] = (f32x4)0.f;

  for (int ks = 0; ks < 4; ++ks) {
    s16x8 qhi[2], qlo[2];
#pragma unroll
    for (int qt = 0; qt < 2; ++qt) {
      int q = qbase + qt * 16 + l15;
      size_t qo = (size_t)q * 128 + ks * 32 + lg * 8;
      f32x4 u0 = *(const f32x4*)(pq0 + qo);
      f32x4 u1 = *(const f32x4*)(pq0 + qo + 4);
      f32x4 w0 = *(const f32x4*)(pq1 + qo);
      f32x4 w1 = *(const f32x4*)(pq1 + qo + 4);
#pragma unroll
      for (int j = 0; j < 8; ++j) {
        float v = ((j < 4) ? (u0[j] + w0[j]) : (u1[j - 4] + w1[j - 4])) * RS;
        unsigned short hh = f2bf(v);
        qhi[qt][j] = (short)hh;
        qlo[qt][j] = (short)f2bf(v - bf2f(hh));
      }
    }
#pragma unroll
    for (int nt = 0; nt < 8; ++nt) {
      s16x8 kb = *(const s16x8*)&lds[(size_t)((ks * 4 + lg) * 128 + nt * 16 + l15) * 8];
#pragma unroll
      for (int qt = 0; qt < 2; ++qt) {
        sc[qt][nt] = __builtin_amdgcn_mfma_f32_16x16x32_bf16(qhi[qt], kb, sc[qt][nt], 0, 0, 0);
        sc[qt][nt] = __builtin_amdgcn_mfma_f32_16x16x32_bf16(qlo[qt], kb, sc[qt][nt], 0, 0, 0);
      }
    }
  }
  // masked softmax (keep k >= q), row distributed over 16 lanes x 8 ntiles
  float inv[2][4];
#pragma unroll
  for (int qt = 0; qt < 2; ++qt) {
#pragma unroll
    for (int r = 0; r < 4; ++r) {
      int q = qbase + qt * 16 + (lg << 2) + r;
      float m = -3.0e38f;
#pragma unroll
      for (int nt = 0; nt < 8; ++nt) {
        int k = nt * 16 + l15;
        float v = sc[qt][nt][r];
        if (k >= q) m = fmaxf(m, v);
      }
#pragma unroll
      for (int d = 1; d < 16; d <<= 1) m = fmaxf(m, __shfl_xor(m, d));
      float ssum = 0.f;
#pragma unroll
      for (int nt = 0; nt < 8; ++nt) {
        int k = nt * 16 + l15;
        float v = sc[qt][nt][r];
        float e = (k >= q) ? __expf(v - m) : 0.f;
        sc[qt][nt][r] = e;
        ssum += e;
      }
#pragma unroll
      for (int d = 1; d < 16; d <<= 1) ssum += __shfl_xor(ssum, d);
      inv[qt][r] = 1.f / ssum;
    }
  }
  __syncthreads();  // all waves done reading Kb
  // write P (alias Kb): blocked [k/8][q][k%8]
#pragma unroll
  for (int qt = 0; qt < 2; ++qt)
#pragma unroll
    for (int nt = 0; nt < 8; ++nt) {
      int k = nt * 16 + l15;
#pragma unroll
      for (int r = 0; r < 4; ++r) {
        int q = qbase + qt * 16 + (lg << 2) + r;
        lds[(size_t)((k >> 3) * 128 + q) * 8 + (k & 7)] = f2bf(sc[qt][nt][r] * inv[qt][r]);
      }
    }
  __syncthreads();
  // PV
  f32x4 o[2][8];
#pragma unroll
  for (int a = 0; a < 2; ++a)
#pragma unroll
    for (int b = 0; b < 8; ++b) o[a][b] = (f32x4)0.f;
  for (int ks = 0; ks < 4; ++ks) {
    s16x8 pa[2];
#pragma unroll
    for (int qt = 0; qt < 2; ++qt)
      pa[qt] = *(const s16x8*)&lds[(size_t)((ks * 4 + lg) * 128 + qbase + qt * 16 + l15) * 8];
#pragma unroll
    for (int nt = 0; nt < 8; ++nt) {
      s16x8 vb = *(const s16x8*)&lds[16384 + (size_t)((ks * 4 + lg) * 128 + nt * 16 + l15) * 8];
      o[0][nt] = __builtin_amdgcn_mfma_f32_16x16x32_bf16(pa[0], vb, o[0][nt], 0, 0, 0);
      o[1][nt] = __builtin_amdgcn_mfma_f32_16x16x32_bf16(pa[1], vb, o[1][nt], 0, 0, 0);
    }
  }
  // store att blocked: attb[(j>>3)*1024 + c*8 + (j&7)], j = h*128+q, c = d
#pragma unroll
  for (int qt = 0; qt < 2; ++qt)
#pragma unroll
    for (int nt = 0; nt < 8; ++nt) {
      int c = nt * 16 + l15;
      int jq = h * 128 + qbase + qt * 16 + (lg << 2);  // j for r=0
      u16x4 pk;
#pragma unroll
      for (int r = 0; r < 4; ++r) pk[r] = f2bf(o[qt][nt][r]);
      *(u16x4*)(att + (size_t)(jq >> 3) * 1024 + c * 8 + (jq & 7)) = pk;
    }
}

// ---------- kernel 3: out += O @ att (split-K=8, k1-twin pipeline) ----------
// grid 512 = 64 rowblocks x 8 kc; block 256 = 4 waves, wave owns 16 rows.
// att (blocked) staged 8KB/step in LDS; O streamed via depth-4 register ring.
__global__ __launch_bounds__(256) void k3_out(const float* __restrict__ O,
                                              const unsigned short* __restrict__ att,
                                              float* __restrict__ out) {
  __shared__ __align__(16) unsigned short ats[4096];  // 8KB
  int bid = blockIdx.x;
  int rb = bid >> 3, kc = bid & 7;
  int r0 = rb * 64;
  int kbase = kc * 512;
  int tid = threadIdx.x, wave = tid >> 6, lane = tid & 63;
  int l15 = lane & 15, lg = lane >> 4;
  int rwb = r0 + wave * 16;
  const float* arow = O + (size_t)(rwb + l15) * DM + lg * 8;
  f32x4 acc[8];
#pragma unroll
  for (int i = 0; i < 8; ++i) acc[i] = (f32x4)0.f;

  u16x8 bb[4][2];
  f32x4 ab[4][2];
#pragma unroll
  for (int p = 0; p < 4; ++p) {
    int kk = kbase + p * 32;
    const u16x8* s = (const u16x8*)(att + (size_t)(kk >> 3) * 1024);
    bb[p][0] = s[tid];
    bb[p][1] = s[256 + tid];
    ab[p][0] = *(const f32x4*)(arow + kk);
    ab[p][1] = *(const f32x4*)(arow + kk + 4);
  }

  for (int tt = 0; tt < 4; ++tt) {
#pragma unroll
    for (int p = 0; p < 4; ++p) {
      int t = tt * 4 + p;
      wave_barrier_lgkm();
      ((u16x8*)ats)[tid] = bb[p][0];
      ((u16x8*)ats)[256 + tid] = bb[p][1];
      s16x8 Ahi, Alo;
#pragma unroll
      for (int j = 0; j < 8; ++j) {
        float v = (j < 4) ? ab[p][0][j] : ab[p][1][j - 4];
        short h, l; splitbf(v, h, l);
        Ahi[j] = h; Alo[j] = l;
      }
      int tp = t + 4;
      int kkp = kbase + ((tp < 16) ? tp : 0) * 32;
      {
        const u16x8* s = (const u16x8*)(att + (size_t)(kkp >> 3) * 1024);
        bb[p][0] = s[tid];
        bb[p][1] = s[256 + tid];
        ab[p][0] = *(const f32x4*)(arow + kkp);
        ab[p][1] = *(const f32x4*)(arow + kkp + 4);
      }
      wave_barrier_lgkm();
#pragma unroll
      for (int nt = 0; nt < 8; ++nt) {
        s16x8 bh = *(const s16x8*)&ats[((lg * 128) + nt * 16 + l15) * 8];
        acc[nt] = __builtin_amdgcn_mfma_f32_16x16x32_bf16(Ahi, bh, acc[nt], 0, 0, 0);
        acc[nt] = __builtin_amdgcn_mfma_f32_16x16x32_bf16(Alo, bh, acc[nt], 0, 0, 0);
      }
    }
  }
#pragma unroll
  for (int nt = 0; nt < 8; ++nt) {
#pragma unroll
    for (int r = 0; r < 4; ++r) {
      int row = rwb + (lg << 2) + r;
      atomicAdd(&out[(size_t)row * 128 + nt * 16 + l15], acc[nt][r]);
    }
  }
}

extern "C" void kernel_launch(void* const* d_in, const int* in_sizes, int n_in,
                              void* d_out, int out_size, void* d_ws, size_t ws_size,
                              hipStream_t stream) {
  const float* Q = (const float*)d_in[0];
  const float* K = (const float*)d_in[1];
  const float* V = (const float*)d_in[2];
  const float* O = (const float*)d_in[3];
  const float* x = (const float*)d_in[4];
  float* out = (float*)d_out;
  uint8_t* ws = (uint8_t*)d_ws;
  unsigned short* xh = (unsigned short*)ws;                        // 1 MB
  unsigned short* att = (unsigned short*)(ws + (1u << 20));        // 1 MB (blocked)
  float* pp = (float*)(ws + (2u << 20));                           // 12 MB
  hipMemsetAsync(d_out, 0, (size_t)out_size * sizeof(float), stream);
  hipLaunchKernelGGL(k0_xsplit, dim3(256), dim3(256), 0, stream, x, xh);
  hipLaunchKernelGGL(k1_proj, dim3(384), dim3(256), 0, stream, Q, K, V, xh, pp);
  hipLaunchKernelGGL(k2_attn, dim3(32), dim3(256), 0, stream, pp, att);
  hipLaunchKernelGGL(k3_out, dim3(512), dim3(256), 0, stream, O, att, out);
}